// Round 13
// baseline (99.661 us; speedup 1.0000x reference)
//
#include <hip/hip_runtime.h>
#include <math.h>

#define IMG   512
#define NIMG  48
#define TB    64            // output tile rows
#define TC    32            // output tile cols
#define SR    74            // stat rows = TB + 10
#define PITCH 77            // odd pitch (R9-validated bijective-bank construction)
#define STS   (TC * PITCH)  // float2 elements per plane
#define C1v   1.0e-4f
#define C2v   9.0e-4f

struct Win { float w[11]; };

// R13: two exact inefficiencies removed.
// 1) Phase-A imbalance: was 592 units/512 threads -> waves 0-1 ran a 2nd full
//    unit while waves 2-7 idled at the barrier (1.73x inflation). Now: main
//    pass = rows 0..63 x 8 quads = exactly 512 units (one per thread, no
//    loop); halo rows 64..73 = 160 half-quad units spread 20 PER WAVE
//    (critical path 2.0 -> ~1.57 units). Half-quad chunk alignment: even half
//    uses local words 3..14, odd half 1..12 -- all 4 chunks fully in-image or
//    fully padding (R8 masking carries over).
// 2) Phase-B plane-split 8-row threads: thread = (col x, row-octet ro, plane
//    pl); reads 18 b64 per 8 outputs (was 28 per 4). Partner lanes +-32
//    exchange S/Q sums via 16 __shfl_xor (in-wave permlane32_swap); each half
//    computes 4 epilogues. Block phase-B LDS ops x0.64.
template<bool GUARD>
__device__ __forceinline__ void phaseA_main(
        float2* __restrict__ hs2,
        const float* __restrict__ P,
        const float* __restrict__ T,
        const Win& win, int bx, int y0, int x0, int tid) {
    const int r  = tid >> 3;            // 0..63
    const int cb = tid & 7;
    const int gy = y0 - 5 + r;          // <= y0+58 <= 506: only low check needed
    const float* __restrict__ Prow = P + (long)gy * IMG;
    const float* __restrict__ Trow = T + (long)gy * IMG;
    const bool yok = (!GUARD) || (gy >= 0);

    float s1[4], s2[4], q1[4], q2[4];
    #pragma unroll
    for (int i = 0; i < 4; ++i) { s1[i]=0.f; s2[i]=0.f; q1[i]=0.f; q2[i]=0.f; }

    #pragma unroll
    for (int k = 0; k < 5; ++k) {       // words 4k..4k+3 (local), words 3..16 used
        float4 p = make_float4(0.f, 0.f, 0.f, 0.f);
        float4 t = make_float4(0.f, 0.f, 0.f, 0.f);
        bool zero = false;
        if (GUARD)
            zero = (!yok) | ((bx == 0)  & (cb + k <= 1))
                          | ((bx == 15) & (cb + k >= 10));
        if (!zero) {
            const int gx = x0 + 4 * (cb + k - 2);
            p = *(const float4*)(Prow + gx);
            t = *(const float4*)(Trow + gx);
        }
        const float pv[4] = { p.x, p.y, p.z, p.w };
        const float tv[4] = { t.x, t.y, t.z, t.w };
        #pragma unroll
        for (int j4 = 0; j4 < 4; ++j4) {
            const int w = 4 * k + j4;
            if (w >= 3 && w <= 16) {
                const float sm = pv[j4] + tv[j4];
                const float dm = pv[j4] - tv[j4];
                const float sq = sm * sm;
                const float dq = dm * dm;
                #pragma unroll
                for (int i = 0; i < 4; ++i) {     // col i uses tap j = w-3-i
                    const int j = w - 3 - i;
                    if (j >= 0 && j < 11) {
                        const float wj = win.w[j];
                        s1[i] += wj * sm;
                        s2[i] += wj * dm;
                        q1[i] += wj * sq;
                        q2[i] += wj * dq;
                    }
                }
            }
        }
    }
    const int ebase = (4 * cb) * PITCH + r;
    #pragma unroll
    for (int i = 0; i < 4; ++i) {
        hs2[ebase + i * PITCH]       = make_float2(s1[i], s2[i]);
        hs2[STS + ebase + i * PITCH] = make_float2(q1[i], q2[i]);
    }
}

template<bool GUARD>
__device__ __forceinline__ void phaseA_tail(
        float2* __restrict__ hs2,
        const float* __restrict__ P,
        const float* __restrict__ T,
        const Win& win, int bx, int y0, int x0, int tid) {
    const int wv = tid >> 6;
    const int l  = tid & 63;
    if (l >= 20) return;                 // 20 half-quad units per wave
    const int u   = wv * 20 + l;         // 0..159
    const int r   = 64 + (u >> 4);       // 64..73
    const int cb2 = u & 15;
    const int cb  = cb2 >> 1;
    const int h   = cb2 & 1;             // half: cols 4cb+2h, 4cb+2h+1
    const int gy  = y0 - 5 + r;          // >= 59: only high check needed
    const float* __restrict__ Prow = P + (long)gy * IMG;
    const float* __restrict__ Trow = T + (long)gy * IMG;
    const bool yok = (!GUARD) || (gy < IMG);
    const int lo = 3 - 2 * h;            // first used local word

    float pa[16], pb[16];
    #pragma unroll
    for (int k = 0; k < 4; ++k) {        // chunk q = cb+h+k
        const int q = cb + h + k;
        float4 p = make_float4(0.f, 0.f, 0.f, 0.f);
        float4 t = make_float4(0.f, 0.f, 0.f, 0.f);
        bool zero = false;
        if (GUARD)
            zero = (!yok) | ((bx == 0)  & (q <= 1))
                          | ((bx == 15) & (q >= 10));
        if (!zero) {
            const int gx = x0 + 4 * (q - 2);
            p = *(const float4*)(Prow + gx);
            t = *(const float4*)(Trow + gx);
        }
        pa[4*k+0] = p.x; pa[4*k+1] = p.y; pa[4*k+2] = p.z; pa[4*k+3] = p.w;
        pb[4*k+0] = t.x; pb[4*k+1] = t.y; pb[4*k+2] = t.z; pb[4*k+3] = t.w;
    }

    float s1[2], s2[2], q1[2], q2[2];
    #pragma unroll
    for (int c = 0; c < 2; ++c) { s1[c]=0.f; s2[c]=0.f; q1[c]=0.f; q2[c]=0.f; }
    #pragma unroll
    for (int m = 0; m < 12; ++m) {       // local word lo+m
        const float a  = pa[lo + m];     // lo is 1 or 3; lo+m <= 14 < 16
        const float b  = pb[lo + m];
        const float sm = a + b;
        const float dm = a - b;
        const float sq = sm * sm;
        const float dq = dm * dm;
        #pragma unroll
        for (int c = 0; c < 2; ++c) {    // col c uses tap j = m - c
            const int j = m - c;
            if (j >= 0 && j < 11) {
                const float wj = win.w[j];
                s1[c] += wj * sm;
                s2[c] += wj * dm;
                q1[c] += wj * sq;
                q2[c] += wj * dq;
            }
        }
    }
    #pragma unroll
    for (int c = 0; c < 2; ++c) {
        const int C = 4 * cb + 2 * h + c;
        hs2[C * PITCH + r]       = make_float2(s1[c], s2[c]);
        hs2[STS + C * PITCH + r] = make_float2(q1[c], q2[c]);
    }
}

__device__ __forceinline__ float ssim_epilogue(float S1, float S2, float Q1, float Q2) {
    const float s1q = S1 * S1;
    const float s2q = S2 * S2;
    const float A_  = 0.5f * (s1q + s2q);     // mu1^2 + mu2^2
    const float B_  = 0.5f * (s1q - s2q);     // 2 mu1 mu2
    const float sps = 0.5f * (Q1 + Q2) - A_;  // sig1^2 + sig2^2
    const float sxx = 0.5f * (Q1 - Q2) - B_;  // 2 sig12
    const float num = (B_ + C1v) * (sxx + C2v);
    const float den = (A_ + C1v) * (sps + C2v);
    return num * __builtin_amdgcn_rcpf(den);
}

__global__ __launch_bounds__(512, 8) void ssim_kernel(
        const float* __restrict__ pred,
        const float* __restrict__ targ,
        float* __restrict__ partial, Win win) {
    __shared__ float2 hs2[2 * STS];
    __shared__ float wavesum[8];

    const int tid = threadIdx.x;
    const int n   = blockIdx.z;
    const int by  = blockIdx.y;
    const int bx  = blockIdx.x;
    const int y0  = by * TB;
    const int x0  = bx * TC;

    const float* __restrict__ P = pred + (size_t)n * IMG * IMG;
    const float* __restrict__ T = targ + (size_t)n * IMG * IMG;

    const bool guard = (bx == 0) | (bx == 15) | (by == 0) | (by == (IMG / TB - 1));
    if (guard) {
        phaseA_main<true >(hs2, P, T, win, bx, y0, x0, tid);
        phaseA_tail<true >(hs2, P, T, win, bx, y0, x0, tid);
    } else {
        phaseA_main<false>(hs2, P, T, win, bx, y0, x0, tid);
        phaseA_tail<false>(hs2, P, T, win, bx, y0, x0, tid);
    }
    __syncthreads();

    // ---- phase B: thread = (col x, row-octet ro, plane pl) ----
    const int x  = tid & 31;
    const int pl = (tid >> 5) & 1;       // lane bit 5 -> partner = lane ^ 32
    const int ro = tid >> 6;             // 0..7
    const int r0 = ro * 8;
    const float2* __restrict__ cp = &hs2[pl * STS + x * PITCH + r0];

    float A0[8], A1[8];                  // this plane's 2 stats x 8 outputs
    #pragma unroll
    for (int k = 0; k < 8; ++k) { A0[k] = 0.f; A1[k] = 0.f; }

    #pragma unroll
    for (int m = 0; m < 18; ++m) {       // stat rows r0..r0+17, ds_read2_b64 pairs
        const float2 v = cp[m];
        #pragma unroll
        for (int k = 0; k < 8; ++k) {    // output k uses tap j = m - k
            const int j = m - k;
            if (j >= 0 && j < 11) {
                const float wj = win.w[j];
                A0[k] += wj * v.x;
                A1[k] += wj * v.y;
            }
        }
    }

    // exchange with partner lane (^32): other plane's sums
    float O0[8], O1[8];
    #pragma unroll
    for (int k = 0; k < 8; ++k) {
        O0[k] = __shfl_xor(A0[k], 32, 64);
        O1[k] = __shfl_xor(A1[k], 32, 64);
    }

    float acc = 0.f;
    if (pl == 0) {                       // own = (S1,S2), other = (Q1,Q2); outputs 0..3
        #pragma unroll
        for (int k = 0; k < 4; ++k)
            acc += ssim_epilogue(A0[k], A1[k], O0[k], O1[k]);
    } else {                             // own = (Q1,Q2), other = (S1,S2); outputs 4..7
        #pragma unroll
        for (int k = 4; k < 8; ++k)
            acc += ssim_epilogue(O0[k], O1[k], A0[k], A1[k]);
    }

    // ---- block reduction (8 waves) ----
    #pragma unroll
    for (int off = 32; off > 0; off >>= 1)
        acc += __shfl_down(acc, off, 64);
    const int wv = tid >> 6;
    if ((tid & 63) == 0) wavesum[wv] = acc;
    __syncthreads();
    if (tid == 0) {
        float s = 0.f;
        #pragma unroll
        for (int i = 0; i < 8; ++i) s += wavesum[i];
        const int bid = (blockIdx.z * gridDim.y + blockIdx.y) * gridDim.x + blockIdx.x;
        partial[bid] = s;
    }
}

__global__ __launch_bounds__(512) void ssim_reduce_kernel(
        const float* __restrict__ partial,
        float* __restrict__ out,
        int nchunk4, double inv_n) {
    __shared__ double wsum[8];
    const float4* __restrict__ p4 = (const float4*)partial;
    double s = 0.0;
    #pragma unroll 1
    for (int i = threadIdx.x; i < nchunk4; i += 512) {
        const float4 v = p4[i];
        s += (double)((v.x + v.y) + (v.z + v.w));
    }
    #pragma unroll
    for (int off = 32; off > 0; off >>= 1)
        s += __shfl_down(s, off, 64);
    const int wv = threadIdx.x >> 6;
    if ((threadIdx.x & 63) == 0) wsum[wv] = s;
    __syncthreads();
    if (threadIdx.x == 0) {
        double tot = 0.0;
        #pragma unroll
        for (int i = 0; i < 8; ++i) tot += wsum[i];
        out[0] = (float)(tot * inv_n);
    }
}

extern "C" void kernel_launch(void* const* d_in, const int* in_sizes, int n_in,
                              void* d_out, int out_size, void* d_ws, size_t ws_size,
                              hipStream_t stream) {
    const float* pred = (const float*)d_in[0];
    const float* targ = (const float*)d_in[1];
    float* out     = (float*)d_out;
    float* partial = (float*)d_ws;   // 16*8*48 = 6144 floats, all written

    Win win;
    {
        double v[11], s = 0.0;
        for (int i = 0; i < 11; ++i) {
            float d   = (float)i - 5.0f;
            float arg = -(d * d) / 4.5f;      // 2*sigma^2 = 4.5
            v[i] = exp((double)arg);
            s += v[i];
        }
        for (int i = 0; i < 11; ++i) win.w[i] = (float)(v[i] / s);
    }

    dim3 grid(IMG / TC, IMG / TB, NIMG);      // (16, 8, 48) = 6144 blocks
    ssim_kernel<<<grid, 512, 0, stream>>>(pred, targ, partial, win);

    const int nblk = (IMG / TC) * (IMG / TB) * NIMG;   // 6144 -> 1536 float4
    const double inv_n = 1.0 / ((double)NIMG * IMG * IMG);
    ssim_reduce_kernel<<<1, 512, 0, stream>>>(partial, out, nblk / 4, inv_n);
}

// Round 14
// 56.677 us; speedup vs baseline: 1.7584x; 1.7584x over previous
//
#include <hip/hip_runtime.h>
#include <math.h>

#define IMG   512
#define NIMG  48
#define TB    64            // output tile rows
#define TC    32            // output tile cols
#define SR    74            // stat rows = TB + 10
#define PITCH 77            // odd pitch (R9-validated bijective-bank construction)
#define STS   (TC * PITCH)  // float2 elements per plane
#define C1v   1.0e-4f
#define C2v   9.0e-4f

typedef __attribute__((ext_vector_type(2))) float f2;

struct Win { float w[11]; };

// R14 = R12 (proven 55.1us; R13's tail/plane-split reverted -- its pa[lo+m]
// runtime index spilled to scratch: WRITE_SIZE 194KB->42.5MB, rule #20)
// + packed-FP32 filter cores: the (s1,s2)/(q1,q2) accumulations share weights,
// so ext_vector float2 math lets the backend emit v_pk_fma_f32/v_pk_mul_f32
// (full-rate VOP3P packed fp32 -- the 157TF path). 176 scalar FMA/unit -> 88
// pk-FMA + 14 pk-mul. Layout, masking, b64 LDS discipline unchanged from R12.
template<bool GUARD>
__device__ __forceinline__ void phaseA_unit(
        f2* __restrict__ hs2,
        const float* __restrict__ P,
        const float* __restrict__ T,
        const Win& win, int bx, int y0, int x0, int u) {
    const int r  = u >> 3;
    const int cb = u & 7;
    const int gy = y0 - 5 + r;
    const float* __restrict__ Prow = P + (long)gy * IMG;
    const float* __restrict__ Trow = T + (long)gy * IMG;
    const bool yok = (!GUARD) || ((gy >= 0) & (gy < IMG));

    f2 accS[4], accQ[4];
    #pragma unroll
    for (int i = 0; i < 4; ++i) { accS[i] = (f2)0.f; accQ[i] = (f2)0.f; }

    // window words 0..19 in 5 aligned 16B chunks; words 3..16 used.
    #pragma unroll
    for (int k = 0; k < 5; ++k) {
        float4 p = make_float4(0.f, 0.f, 0.f, 0.f);
        float4 t = make_float4(0.f, 0.f, 0.f, 0.f);
        bool zero = false;
        if (GUARD)   // every 16B chunk fully in-image or fully padding (R8-proven)
            zero = (!yok) | ((bx == 0)  & (cb + k <= 1))
                          | ((bx == 15) & (cb + k >= 10));
        if (!zero) {
            const int gx = x0 + 4 * (cb + k - 2);
            p = *(const float4*)(Prow + gx);
            t = *(const float4*)(Trow + gx);
        }
        const float pv[4] = { p.x, p.y, p.z, p.w };
        const float tv[4] = { t.x, t.y, t.z, t.w };
        #pragma unroll
        for (int j4 = 0; j4 < 4; ++j4) {
            const int w = 4 * k + j4;
            if (w >= 3 && w <= 16) {
                f2 sd;
                sd.x = pv[j4] + tv[j4];
                sd.y = pv[j4] - tv[j4];
                const f2 qq = sd * sd;            // v_pk_mul_f32
                #pragma unroll
                for (int i = 0; i < 4; ++i) {     // col i uses tap j = w-3-i
                    const int j = w - 3 - i;
                    if (j >= 0 && j < 11) {
                        const float wj = win.w[j];
                        accS[i] += wj * sd;       // v_pk_fma_f32 (scalar splat)
                        accQ[i] += wj * qq;
                    }
                }
            }
        }
    }
    // paired b64 stores: elem = plane*STS + (4cb+i)*PITCH + r
    const int ebase = (4 * cb) * PITCH + r;
    #pragma unroll
    for (int i = 0; i < 4; ++i) {
        hs2[ebase + i * PITCH]       = accS[i];
        hs2[STS + ebase + i * PITCH] = accQ[i];
    }
}

__global__ __launch_bounds__(512, 8) void ssim_kernel(
        const float* __restrict__ pred,
        const float* __restrict__ targ,
        float* __restrict__ partial, Win win) {
    __shared__ f2 hs2[2 * STS];
    __shared__ float wavesum[8];

    const int tid = threadIdx.x;
    const int n   = blockIdx.z;
    const int by  = blockIdx.y;
    const int bx  = blockIdx.x;
    const int y0  = by * TB;
    const int x0  = bx * TC;

    const float* __restrict__ P = pred + (size_t)n * IMG * IMG;
    const float* __restrict__ T = targ + (size_t)n * IMG * IMG;

    // ---- phase A: H-pass from global; unit = (stat row r, col-quad cb) ----
    const bool guard = (bx == 0) | (bx == 15) | (by == 0) | (by == (IMG / TB - 1));
    if (guard) {
        #pragma unroll 1
        for (int u = tid; u < SR * 8; u += 512)
            phaseA_unit<true >(hs2, P, T, win, bx, y0, x0, u);
    } else {
        #pragma unroll 1
        for (int u = tid; u < SR * 8; u += 512)
            phaseA_unit<false>(hs2, P, T, win, bx, y0, x0, u);
    }
    __syncthreads();

    // ---- phase B: V-pass; thread = (col x, 4 output rows), b64 reads ----
    const int x  = tid & 31;
    const int rg = tid >> 5;            // 0..15
    const int r0 = rg * 4;
    const f2* __restrict__ csd = &hs2[x * PITCH + r0];         // (s1,s2)
    const f2* __restrict__ cqq = &hs2[STS + x * PITCH + r0];   // (q1,q2)

    f2 sumS[4], sumQ[4];
    #pragma unroll
    for (int k = 0; k < 4; ++k) { sumS[k] = (f2)0.f; sumQ[k] = (f2)0.f; }

    #pragma unroll
    for (int m = 0; m < 14; ++m) {      // consecutive elems -> ds_read2_b64
        const f2 sd = csd[m];
        const f2 qq = cqq[m];
        #pragma unroll
        for (int k = 0; k < 4; ++k) {   // output k uses tap j = m - k
            const int j = m - k;
            if (j >= 0 && j < 11) {
                const float wj = win.w[j];
                sumS[k] += wj * sd;     // v_pk_fma_f32
                sumQ[k] += wj * qq;
            }
        }
    }

    float acc = 0.f;
    #pragma unroll
    for (int k = 0; k < 4; ++k) {
        const f2 sq = sumS[k] * sumS[k];          // (S1^2, S2^2) pk
        const float A_  = 0.5f * (sq.x + sq.y);   // mu1^2 + mu2^2
        const float B_  = 0.5f * (sq.x - sq.y);   // 2 mu1 mu2
        const float Q1 = sumQ[k].x;
        const float Q2 = sumQ[k].y;
        const float sps = 0.5f * (Q1 + Q2) - A_;  // sig1^2 + sig2^2
        const float sxx = 0.5f * (Q1 - Q2) - B_;  // 2 sig12
        const float num = (B_ + C1v) * (sxx + C2v);
        const float den = (A_ + C1v) * (sps + C2v);
        acc += num * __builtin_amdgcn_rcpf(den);
    }

    // ---- block reduction (8 waves) ----
    #pragma unroll
    for (int off = 32; off > 0; off >>= 1)
        acc += __shfl_down(acc, off, 64);
    const int wv = tid >> 6;
    if ((tid & 63) == 0) wavesum[wv] = acc;
    __syncthreads();
    if (tid == 0) {
        float s = 0.f;
        #pragma unroll
        for (int i = 0; i < 8; ++i) s += wavesum[i];
        const int bid = (blockIdx.z * gridDim.y + blockIdx.y) * gridDim.x + blockIdx.x;
        partial[bid] = s;
    }
}

__global__ __launch_bounds__(512) void ssim_reduce_kernel(
        const float* __restrict__ partial,
        float* __restrict__ out,
        int nchunk4, double inv_n) {
    __shared__ double wsum[8];
    const float4* __restrict__ p4 = (const float4*)partial;
    double s = 0.0;
    #pragma unroll 1
    for (int i = threadIdx.x; i < nchunk4; i += 512) {
        const float4 v = p4[i];
        s += (double)((v.x + v.y) + (v.z + v.w));
    }
    #pragma unroll
    for (int off = 32; off > 0; off >>= 1)
        s += __shfl_down(s, off, 64);
    const int wv = threadIdx.x >> 6;
    if ((threadIdx.x & 63) == 0) wsum[wv] = s;
    __syncthreads();
    if (threadIdx.x == 0) {
        double tot = 0.0;
        #pragma unroll
        for (int i = 0; i < 8; ++i) tot += wsum[i];
        out[0] = (float)(tot * inv_n);
    }
}

extern "C" void kernel_launch(void* const* d_in, const int* in_sizes, int n_in,
                              void* d_out, int out_size, void* d_ws, size_t ws_size,
                              hipStream_t stream) {
    const float* pred = (const float*)d_in[0];
    const float* targ = (const float*)d_in[1];
    float* out     = (float*)d_out;
    float* partial = (float*)d_ws;   // 16*8*48 = 6144 floats, all written

    Win win;
    {
        double v[11], s = 0.0;
        for (int i = 0; i < 11; ++i) {
            float d   = (float)i - 5.0f;
            float arg = -(d * d) / 4.5f;      // 2*sigma^2 = 4.5
            v[i] = exp((double)arg);
            s += v[i];
        }
        for (int i = 0; i < 11; ++i) win.w[i] = (float)(v[i] / s);
    }

    dim3 grid(IMG / TC, IMG / TB, NIMG);      // (16, 8, 48) = 6144 blocks
    ssim_kernel<<<grid, 512, 0, stream>>>(pred, targ, partial, win);

    const int nblk = (IMG / TC) * (IMG / TB) * NIMG;   // 6144 -> 1536 float4
    const double inv_n = 1.0 / ((double)NIMG * IMG * IMG);
    ssim_reduce_kernel<<<1, 512, 0, stream>>>(partial, out, nblk / 4, inv_n);
}